// Round 4
// baseline (178.364 us; speedup 1.0000x reference)
//
#include <hip/hip_runtime.h>

#define NNODES 10000
#define NEDGES 160000
#define NB 8
#define NC 32
#define PADE 230016   // >= NEDGES + 7*NNODES (buckets padded to multiple of 8)
constexpr float NEG_SLOPE = 0.01f;

__device__ __forceinline__ float sigmoidf_(float x) {
    return 1.0f / (1.0f + __expf(-x));
}

// ---- setup: zero counters, sentinel-fill sorted arrays, fold attention weights ----
// consts: [0:32) aq1, [32:64) ak1, [64:96) aq2, [96:128) ak2, [128] ce1, [129] ce2
__global__ __launch_bounds__(256) void setup_kernel(
    const float* Q1, const float* K1, const float* aw1, const float* We1,
    const float* Q2, const float* K2, const float* aw2, const float* We2,
    float* consts,
    int* srcs1, int* srcs2, float* ws1, float* ws2,
    int* cnt,
    float* xs1, float* xs2,
    float* sq1, float* sk1, float* sq2, float* sk2)
{
    if (blockIdx.x == gridDim.x - 1) {
        int t = threadIdx.x;
        if (t < 32) {
            float aq1 = 0.f, ak1 = 0.f, aq2 = 0.f, ak2 = 0.f;
            for (int s = 0; s < 32; ++s) {
                aq1 += Q1[t * 32 + s] * aw1[s];
                ak1 += K1[t * 32 + s] * aw1[32 + s];
                aq2 += Q2[t * 32 + s] * aw2[s];
                ak2 += K2[t * 32 + s] * aw2[32 + s];
            }
            consts[t]      = aq1;
            consts[32 + t] = ak1;
            consts[64 + t] = aq2;
            consts[96 + t] = ak2;
            if (t == 0) {
                float ce1 = 0.f, ce2 = 0.f;
                for (int s = 0; s < 32; ++s) {
                    ce1 += We1[s] * aw1[64 + s];
                    ce2 += We2[s] * aw2[64 + s];
                }
                consts[128] = ce1;
                consts[129] = ce2;
            }
        }
        return;
    }
    int i = blockIdx.x * 256 + threadIdx.x;
    if (i < PADE) {
        srcs1[i] = NNODES; srcs2[i] = NNODES;
        ws1[i] = 0.f;      ws2[i] = 0.f;
    }
    if (i < 2 * NNODES) cnt[i] = 0;
    if (i < NB * NC) {
        xs1[(size_t)NNODES * NB * NC + i] = 0.f;
        xs2[(size_t)NNODES * NB * NC + i] = 0.f;
    }
    if (i < NB) {
        sq1[NNODES * NB + i] = 0.f; sk1[NNODES * NB + i] = 0.f;
        sq2[NNODES * NB + i] = 0.f; sk2[NNODES * NB + i] = 0.f;
    }
}

__global__ __launch_bounds__(256) void hist_kernel(
    const int* __restrict__ ei0, const int* __restrict__ ei1, int* __restrict__ cnt01)
{
    int e = blockIdx.x * 256 + threadIdx.x;
    const int* ei = blockIdx.y ? ei1 : ei0;
    int* cnt = cnt01 + blockIdx.y * NNODES;
    if (e < NEDGES) atomicAdd(&cnt[ei[NEDGES + e]], 1);
}

// block per layer: exclusive scan of counts rounded up to multiple of 8
__global__ __launch_bounds__(1024) void scan_kernel(int* cnt01, int* rowptr01)
{
    __shared__ int part[1024];
    int layer = blockIdx.x;
    int* cnt    = cnt01 + layer * NNODES;
    int* rowptr = rowptr01 + layer * (NNODES + 1);
    int t = threadIdx.x;
    int base = t * 10;
    int local[10];
    int s = 0;
    #pragma unroll
    for (int i = 0; i < 10; ++i) {
        int idx = base + i;
        int v = (idx < NNODES) ? cnt[idx] : 0;
        int vp = (v + 7) & ~7;          // pad to multiple of 8
        local[i] = s;
        s += vp;
    }
    part[t] = s;
    __syncthreads();
    for (int off = 1; off < 1024; off <<= 1) {
        int v = (t >= off) ? part[t - off] : 0;
        __syncthreads();
        part[t] += v;
        __syncthreads();
    }
    int pre = (t == 0) ? 0 : part[t - 1];
    #pragma unroll
    for (int i = 0; i < 10; ++i) {
        int idx = base + i;
        if (idx < NNODES) {
            int p = pre + local[i];
            rowptr[idx] = p;
            cnt[idx]    = p;            // becomes scatter cursor
        }
    }
    if (t == 1023) rowptr[NNODES] = part[1023];
}

__global__ __launch_bounds__(256) void scatter_kernel(
    const int* __restrict__ ei0, const int* __restrict__ ei1,
    const float* __restrict__ ew0, const float* __restrict__ ew1,
    int* __restrict__ cur01,
    int* __restrict__ srcs1, int* __restrict__ srcs2,
    float* __restrict__ ws1, float* __restrict__ ws2)
{
    int e = blockIdx.x * 256 + threadIdx.x;
    int layer = blockIdx.y;
    const int*   ei = layer ? ei1 : ei0;
    const float* ew = layer ? ew1 : ew0;
    int*   cur  = cur01 + layer * NNODES;
    int*   srcs = layer ? srcs2 : srcs1;
    float* ws   = layer ? ws2 : ws1;
    if (e < NEDGES) {
        int dst = ei[NEDGES + e];
        int pos = atomicAdd(&cur[dst], 1);
        srcs[pos] = ei[e];
        ws[pos]   = ew[e];
    }
}

// wave-per-node: xs = X @ Wn ; sq = xs.aq ; sk = xs.ak   (X is [B,N,C])
__global__ __launch_bounds__(256) void node_transform_kernel(
    const float* __restrict__ X, float* __restrict__ xs,
    const float* __restrict__ Wn, const float* __restrict__ consts,
    float* __restrict__ sq, float* __restrict__ sk)
{
    __shared__ float wnL[NC * NC];
    __shared__ float xrow[4][NB][NC + 4];
    int t = threadIdx.x, w = t >> 6, l = t & 63, b = l >> 3, o4 = l & 7;
    int n = blockIdx.x * 4 + w;
    for (int i = t; i < NC * NC; i += 256) wnL[i] = Wn[i];
    const float4* X4 = (const float4*)X;
    float4 xv = X4[((size_t)b * NNODES + n) * 8 + o4];
    ((float4*)&xrow[w][b][0])[o4] = xv;
    __syncthreads();
    float4 aq = ((const float4*)(consts + 0))[o4];
    float4 ak = ((const float4*)(consts + 32))[o4];
    const float4* wnL4 = (const float4*)wnL;
    float4 acc = {0.f, 0.f, 0.f, 0.f};
    #pragma unroll
    for (int c = 0; c < NC; ++c) {
        float xc = xrow[w][b][c];
        float4 w4 = wnL4[c * 8 + o4];
        acc.x += xc * w4.x; acc.y += xc * w4.y;
        acc.z += xc * w4.z; acc.w += xc * w4.w;
    }
    ((float4*)xs)[(size_t)n * 64 + l] = acc;
    float vq = acc.x * aq.x + acc.y * aq.y + acc.z * aq.z + acc.w * aq.w;
    float vk = acc.x * ak.x + acc.y * ak.y + acc.z * ak.z + acc.w * ak.w;
    #pragma unroll
    for (int m = 4; m >= 1; m >>= 1) {
        vq += __shfl_xor(vq, m);
        vk += __shfl_xor(vk, m);
    }
    if (o4 == 0) {
        sq[n * NB + b] = vq;
        sk[n * NB + b] = vk;
    }
}

// wave per node (4 nodes/block): att[e,b] = sigmoid(sq[src]+sk[dst]+w*ce+ab)
// lane = (j: 8 edges, bb: 8 batches); writes 256B coalesced per chunk.
__global__ __launch_bounds__(256) void att_kernel(
    const int* __restrict__ rowptr, const int* __restrict__ srcs,
    const float* __restrict__ wsrt,
    const float* __restrict__ sq, const float* __restrict__ sk,
    const float* __restrict__ attb, const float* __restrict__ consts, int ceoff,
    float* __restrict__ attS)
{
    int t = threadIdx.x, w = t >> 6, l = t & 63;
    int n = blockIdx.x * 4 + w;
    int j = l >> 3, bb = l & 7;
    float ab = attb[0], ce = consts[ceoff];
    float skb = sk[n * NB + bb];
    int row0 = rowptr[n], degp = rowptr[n + 1] - row0;
    const int*   srcp = srcs + row0;
    const float* wp   = wsrt + row0;
    float* ap = attS + (size_t)row0 * NB;
    for (int c0 = 0; c0 < degp; c0 += 8) {
        int s    = srcp[c0 + j];
        float wj = wp[c0 + j];
        ap[(size_t)(c0 + j) * NB + bb] = sigmoidf_(sq[s * NB + bb] + skb + wj * ce + ab);
    }
}

// Gather: block = 2 nodes x 4 waves; wave = (node, 4 batches); lane = (b4, o2) float2.
// Inner loop: 8 fully-unrolled edges per chunk, next-chunk src/w/att prefetched.
// MODE 0: fuse layer-2 node transform. MODE 1: final output [B,N,C].
template <int MODE>
__global__ __launch_bounds__(256) void gather_kernel(
    const int* __restrict__ rowptr, const int* __restrict__ srcs,
    const float* __restrict__ wsrt, const float* __restrict__ attS,
    const float* __restrict__ xs,
    const float* __restrict__ We, const float* __restrict__ consts,
    const float* __restrict__ ow, const float* __restrict__ ob,
    const float* __restrict__ Wn2,
    float* __restrict__ xs2, float* __restrict__ sq2, float* __restrict__ sk2,
    float* __restrict__ outp)
{
    __shared__ float owL[2 * NC * NC];                 // 8 KB
    __shared__ float wnL[(MODE == 0) ? NC * NC : 4];   // 4 KB (MODE 0)
    __shared__ float hL[2][NB][NC + 2];
    __shared__ float aL[2][NB][NC + 2];

    int t = threadIdx.x, w = t >> 6, l = t & 63;
    int n2 = w >> 1;
    int n = blockIdx.x * 2 + n2;
    int boff = (w & 1) * 4;
    int b4 = l >> 4, b = boff + b4, o2 = l & 15;

    for (int i = t; i < 2 * NC * NC; i += 256) owL[i] = ow[i];
    if (MODE == 0)
        for (int i = t; i < NC * NC; i += 256) wnL[i] = Wn2[i];

    float2 we2 = ((const float2*)We)[o2];
    int row0 = rowptr[n];
    int degp = rowptr[n + 1] - row0;       // multiple of 8
    const float2* X2   = (const float2*)xs;
    const int*    srcp = srcs + row0;
    const float*  wp   = wsrt + row0;
    const float*  attp = attS + (size_t)row0 * NB;

    float2 acc = {0.f, 0.f};
    int sv_c = NNODES; float wv_c = 0.f, av_c = 0.f;
    if (degp > 0) {
        if (l < 8)  { sv_c = srcp[l]; wv_c = wp[l]; }
        if (l < 32) av_c = attp[(size_t)(l >> 2) * NB + boff + (l & 3)];
    }
    for (int c0 = 0; c0 < degp; c0 += 8) {
        int sv_n = NNODES; float wv_n = 0.f, av_n = 0.f;
        int c1 = c0 + 8;
        if (c1 < degp) {
            if (l < 8)  { sv_n = srcp[c1 + l]; wv_n = wp[c1 + l]; }
            if (l < 32) av_n = attp[(size_t)(c1 + (l >> 2)) * NB + boff + (l & 3)];
        }
        #pragma unroll
        for (int j = 0; j < 8; ++j) {
            int   s  = __shfl(sv_c, j);
            float wj = __shfl(wv_c, j);
            float at = __shfl(av_c, j * 4 + b4);
            float2 x2 = X2[((size_t)s * NB + b) * 16 + o2];
            acc.x += at * sigmoidf_(wj * we2.x) * x2.x;
            acc.y += at * sigmoidf_(wj * we2.y) * x2.y;
        }
        sv_c = sv_n; wv_c = wv_n; av_c = av_n;
    }

    // stage xd row + aggregate row
    ((float2*)&hL[n2][b][0])[o2] = X2[((size_t)n * NB + b) * 16 + o2];
    ((float2*)&aL[n2][b][0])[o2] = acc;
    __syncthreads();

    // remapped epilogue threads: (tn2, tb, to2)
    int tn2 = t >> 7, tb = (t >> 4) & 7, to2 = t & 15;
    int bn = blockIdx.x * 2 + tn2;
    float2 u = ((const float2*)ob)[to2];
    #pragma unroll
    for (int c = 0; c < NC; ++c) {
        float xc = hL[tn2][tb][c];
        float ac = aL[tn2][tb][c];
        float2 w1 = ((const float2*)(owL + c * NC))[to2];
        float2 w2 = ((const float2*)(owL + (NC + c) * NC))[to2];
        u.x += xc * w1.x + ac * w2.x;
        u.y += xc * w1.y + ac * w2.y;
    }
    float2 xv = ((float2*)&hL[tn2][tb][0])[to2];
    float2 r;
    r.x = xv.x + u.x; r.y = xv.y + u.y;
    r.x = (r.x > 0.f) ? r.x : NEG_SLOPE * r.x;
    r.y = (r.y > 0.f) ? r.y : NEG_SLOPE * r.y;

    if (MODE == 1) {
        ((float2*)outp)[((size_t)tb * NNODES + bn) * 16 + to2] = r;
    } else {
        __syncthreads();
        ((float2*)&hL[tn2][tb][0])[to2] = r;   // h row replaces xd row
        __syncthreads();
        float2 a2 = {0.f, 0.f};
        #pragma unroll
        for (int c = 0; c < NC; ++c) {
            float hc = hL[tn2][tb][c];
            float2 w4 = ((const float2*)(wnL + c * NC))[to2];
            a2.x += hc * w4.x;
            a2.y += hc * w4.y;
        }
        ((float2*)xs2)[((size_t)bn * NB + tb) * 16 + to2] = a2;
        float2 aq = ((const float2*)(consts + 64))[to2];
        float2 ak = ((const float2*)(consts + 96))[to2];
        float vq = a2.x * aq.x + a2.y * aq.y;
        float vk = a2.x * ak.x + a2.y * ak.y;
        #pragma unroll
        for (int m = 8; m >= 1; m >>= 1) {
            vq += __shfl_xor(vq, m);
            vk += __shfl_xor(vk, m);
        }
        if (to2 == 0) {
            sq2[bn * NB + tb] = vq;
            sk2[bn * NB + tb] = vk;
        }
    }
}

extern "C" void kernel_launch(void* const* d_in, const int* in_sizes, int n_in,
                              void* d_out, int out_size, void* d_ws, size_t ws_size,
                              hipStream_t stream) {
    const float* X    = (const float*)d_in[0];
    const int*   ei0  = (const int*)  d_in[1];
    const int*   ei1  = (const int*)  d_in[2];
    const float* ew0  = (const float*)d_in[3];
    const float* ew1  = (const float*)d_in[4];
    const float* Wn1  = (const float*)d_in[7];
    const float* We1  = (const float*)d_in[8];
    const float* Q1   = (const float*)d_in[9];
    const float* K1   = (const float*)d_in[10];
    const float* aw1  = (const float*)d_in[11];
    const float* ab1  = (const float*)d_in[12];
    const float* ow1  = (const float*)d_in[13];
    const float* ob1  = (const float*)d_in[14];
    const float* Wn2  = (const float*)d_in[15];
    const float* We2  = (const float*)d_in[16];
    const float* Q2   = (const float*)d_in[17];
    const float* K2   = (const float*)d_in[18];
    const float* aw2  = (const float*)d_in[19];
    const float* ab2  = (const float*)d_in[20];
    const float* ow2  = (const float*)d_in[21];
    const float* ob2  = (const float*)d_in[22];

    const size_t ROW = (size_t)(NNODES + 1) * NB * NC;   // 2,560,256
    const size_t SS  = (size_t)(NNODES + 1) * NB;        // 80,008
    float* XS1    = (float*)d_ws;
    float* XS2    = XS1 + ROW;
    float* SQ1    = XS2 + ROW;
    float* SK1    = SQ1 + SS;
    float* SQ2    = SK1 + SS;
    float* SK2    = SQ2 + SS;
    float* CONSTS = SK2 + SS;                            // 160
    int* ROWPTR1  = (int*)(CONSTS + 160);
    int* ROWPTR2  = ROWPTR1 + (NNODES + 1);
    int* CNT      = ROWPTR2 + (NNODES + 1);              // 2*N
    int* SRCS1    = CNT + 2 * NNODES;
    int* SRCS2    = SRCS1 + PADE;
    float* WS1    = (float*)(SRCS2 + PADE);
    float* WS2    = WS1 + PADE;
    float* ATT    = WS2 + PADE;                          // PADE*8 floats (shared by both layers)

    const int EBLKS = (NEDGES + 255) / 256;              // 625
    const int FILLB = (PADE + 255) / 256;                // 899

    setup_kernel<<<FILLB + 1, 256, 0, stream>>>(
        Q1, K1, aw1, We1, Q2, K2, aw2, We2, CONSTS,
        SRCS1, SRCS2, WS1, WS2, CNT, XS1, XS2, SQ1, SK1, SQ2, SK2);
    hist_kernel<<<dim3(EBLKS, 2), 256, 0, stream>>>(ei0, ei1, CNT);
    scan_kernel<<<2, 1024, 0, stream>>>(CNT, ROWPTR1);
    scatter_kernel<<<dim3(EBLKS, 2), 256, 0, stream>>>(
        ei0, ei1, ew0, ew1, CNT, SRCS1, SRCS2, WS1, WS2);
    node_transform_kernel<<<NNODES / 4, 256, 0, stream>>>(X, XS1, Wn1, CONSTS, SQ1, SK1);

    att_kernel<<<NNODES / 4, 256, 0, stream>>>(
        ROWPTR1, SRCS1, WS1, SQ1, SK1, ab1, CONSTS, 128, ATT);
    gather_kernel<0><<<NNODES / 2, 256, 0, stream>>>(
        ROWPTR1, SRCS1, WS1, ATT, XS1, We1, CONSTS, ow1, ob1,
        Wn2, XS2, SQ2, SK2, nullptr);

    att_kernel<<<NNODES / 4, 256, 0, stream>>>(
        ROWPTR2, SRCS2, WS2, SQ2, SK2, ab2, CONSTS, 129, ATT);
    gather_kernel<1><<<NNODES / 2, 256, 0, stream>>>(
        ROWPTR2, SRCS2, WS2, ATT, XS2, We2, CONSTS, ow2, ob2,
        nullptr, nullptr, nullptr, nullptr, (float*)d_out);
}